// Round 4
// baseline (386.064 us; speedup 1.0000x reference)
//
#include <hip/hip_runtime.h>
#include <math.h>

#define Bv 256
#define Tv 16
#define Fv 8
#define Dv 32
#define Kv 64
#define Cv 1024
#define Ov 2
#define D1 33   // D+1

typedef unsigned long long u64;
typedef unsigned char u8;

struct SM {
  float ccs[Fv * Kv];        // ||center||^2 per (ff,k)   2 KB
  u64   cds[Tv];             // packed code bytes per t (written via u8 alias)
  float srep_all[Fv * D1];   // cali blocks: srep slices for all f
  float vsum[D1];
  float qs[Dv], iqs[Dv], zs[D1 + 1];
  float redm[4], reds[4];
  int   fm_arr[Fv];
  int   fm_any;
  int   anyf[4];
};

// ---------------------------------------------------------------------------
// Compute VQ codes for batch b into sm.cds (byte-packed u64 per t).
// 2 threads per (t,ff) argmin (each scans 32 centers), first-index tiebreak
// matching jnp.argmin. Ends with __syncthreads().
// ---------------------------------------------------------------------------
__device__ __forceinline__ void compute_codes(
    SM& sm, int b, const float* __restrict__ tdata,
    const int* __restrict__ f_mask, const float* __restrict__ centers) {
  int tid = threadIdx.x;
  // ||c||^2 table: 512 entries, 2 per thread
  #pragma unroll
  for (int r = 0; r < 2; r++) {
    int idx = tid + r * 256;
    const float* cr = centers + idx * Dv;   // idx = ff*64+k
    float s = 0.f;
    #pragma unroll
    for (int j = 0; j < Dv; j++) { float cv = cr[j]; s += cv * cv; }
    sm.ccs[idx] = s;
  }
  int pair = tid >> 1, half = tid & 1;
  int t = pair >> 3, ff = pair & 7;
  int bt = b * Tv + t;
  const float4* xr = (const float4*)(tdata + (size_t)(bt * Fv + ff) * Dv);
  float4 xq[8];
  #pragma unroll
  for (int i = 0; i < 8; i++) xq[i] = xr[i];
  __syncthreads();
  int k0 = half * 32;
  const float4* cb = (const float4*)(centers + (size_t)(ff * Kv + k0) * Dv);
  float dmin = INFINITY; int kmin = k0;
  for (int k = 0; k < 32; k++) {
    const float4* cr = cb + k * 8;
    float4 dv = make_float4(0.f, 0.f, 0.f, 0.f);
    #pragma unroll
    for (int i = 0; i < 8; i++) {
      float4 cq = cr[i];
      dv.x += xq[i].x * cq.x; dv.y += xq[i].y * cq.y;
      dv.z += xq[i].z * cq.z; dv.w += xq[i].w * cq.w;
    }
    float dot = (dv.x + dv.y) + (dv.z + dv.w);
    float d = sm.ccs[ff * Kv + k0 + k] - 2.0f * dot;
    if (d < dmin) { dmin = d; kmin = k0 + k; }   // strict <: first index wins
  }
  float od = __shfl_xor(dmin, 1, 64);
  int ok = __shfl_xor(kmin, 1, 64);
  if (od < dmin || (od == dmin && ok < kmin)) { dmin = od; kmin = ok; }
  if (half == 0) {
    int m = f_mask[bt * Fv + ff];
    ((u8*)sm.cds)[t * Fv + ff] = (u8)(m != 0 ? kmin + 2 : 1);
  }
  __syncthreads();
}

// ---------------------------------------------------------------------------
// Per-feature attention. Requires sm.cds valid and *fm_flag written before
// the caller's last sync (or before this function's first internal sync).
// Leaves final srep slice in sm.vsum[0..32]. If write_out: also writes the
// a_all row and srep global. Branches are block-uniform. No trailing sync.
// ---------------------------------------------------------------------------
__device__ __forceinline__ void attn_feature(
    SM& sm, int b, int f, bool write_out, const int* fm_flag,
    const float* __restrict__ tdata,
    const int* __restrict__ pat, const float* __restrict__ pat_rep,
    const float* __restrict__ pos_cnt, const float* __restrict__ neg_cnt,
    const float* __restrict__ W_q, const float* __restrict__ b_q,
    const float* __restrict__ W_k, const float* __restrict__ b_k,
    const float* __restrict__ W_v, const float* __restrict__ b_v,
    float* __restrict__ a_out, float* __restrict__ srep_out) {
  int tid = threadIdx.x;
  if (tid < 4) sm.anyf[tid] = 0;

  u64 creg[Tv];
  #pragma unroll
  for (int t = 0; t < Tv; t++) creg[t] = sm.cds[t];

  int c0 = tid * 4;
  const int* pbase = pat + ((size_t)f * Cv + c0) * Fv;
  u64 pp[4], cm[4];
  #pragma unroll
  for (int j = 0; j < 4; j++) {
    int4 pa = ((const int4*)(pbase + j * Fv))[0];
    int4 pb = ((const int4*)(pbase + j * Fv))[1];
    int vals[8] = {pa.x, pa.y, pa.z, pa.w, pb.x, pb.y, pb.z, pb.w};
    u64 P = 0, M = 0;
    #pragma unroll
    for (int ff = 0; ff < Fv; ff++) {
      P |= ((u64)(vals[ff] & 0xFF)) << (8 * ff);
      if (vals[ff] != 0) M |= 0xFFull << (8 * ff);
    }
    pp[j] = P; cm[j] = M;
  }
  bool mt[4];
  #pragma unroll
  for (int j = 0; j < 4; j++) {
    bool m = false;
    #pragma unroll
    for (int t = 0; t < Tv; t++) m = m || (((creg[t] ^ pp[j]) & cm[j]) == 0ull);
    mt[j] = m;
  }
  bool lany = mt[0] || mt[1] || mt[2] || mt[3];
  __syncthreads();                       // anyf zero + fm_flag visible
  bool wv = __any((int)lany);
  if ((tid & 63) == 0) sm.anyf[tid >> 6] = wv ? 1 : 0;
  __syncthreads();
  bool anym = (sm.anyf[0] | sm.anyf[1] | sm.anyf[2] | sm.anyf[3]) != 0;
  bool fm = (*fm_flag) != 0;

  float4* arow = (float4*)(a_out + (size_t)(f * Bv + b) * Cv);

  if (!anym) {
    // ----------- common (degenerate) path -----------
    if (write_out) {
      const float u = 1.0f / 1024.0f;
      arow[tid] = make_float4(u, u, u, u);
    }
    if (tid < D1) {
      float vd = fm ? b_v[f * D1 + tid] : 0.f;
      sm.vsum[tid] = vd;
      if (write_out) srep_out[(b * Fv + f) * D1 + tid] = vd;
    }
    return;
  }

  // ----------- rare full path -----------
  if (tid < D1) sm.vsum[tid] = 0.f;
  if (tid < Dv) sm.qs[tid] = tdata[((b * Tv + (Tv - 1)) * Fv + f) * Dv + tid];
  __syncthreads();
  if (tid < Dv) {
    const float* w = W_q + (f * Dv + tid) * Dv;
    float s = b_q[f * Dv + tid];
    #pragma unroll
    for (int j = 0; j < Dv; j++) s += w[j] * sm.qs[j];
    sm.iqs[tid] = s;
  }
  __syncthreads();
  if (tid < D1) {
    float s = 0.f;
    #pragma unroll
    for (int i = 0; i < Dv; i++) s += W_k[(f * Dv + i) * D1 + tid] * sm.iqs[i];
    sm.zs[tid] = s;
  }
  if (tid == D1) {
    float s = 0.f;
    #pragma unroll
    for (int i = 0; i < Dv; i++) s += b_k[f * Dv + i] * sm.iqs[i];
    sm.zs[D1] = s;
  }
  __syncthreads();

  float ev[4];
  float lmax = -INFINITY;
  #pragma unroll
  for (int j = 0; j < 4; j++) {
    ev[j] = 0.f;
    if (mt[j]) {
      int c = c0 + j;
      const float* rp = pat_rep + (size_t)(f * Cv + c) * Dv;
      float p = pos_cnt[f * Cv + c], n = neg_cnt[f * Cv + c];
      float r = p / (p + n + 1e-6f);
      float s = sm.zs[D1] + r * sm.zs[Dv];
      for (int jj = 0; jj < Dv; jj++) s += rp[jj] * sm.zs[jj];
      ev[j] = s;
      lmax = fmaxf(lmax, s);
    }
  }
  float mx = lmax;
  #pragma unroll
  for (int off = 32; off >= 1; off >>= 1) mx = fmaxf(mx, __shfl_xor(mx, off, 64));
  if ((tid & 63) == 0) sm.redm[tid >> 6] = mx;
  __syncthreads();
  float bmax = fmaxf(fmaxf(sm.redm[0], sm.redm[1]), fmaxf(sm.redm[2], sm.redm[3]));

  float av[4] = {0.f, 0.f, 0.f, 0.f};
  float ls = 0.f;
  #pragma unroll
  for (int j = 0; j < 4; j++) {
    if (mt[j]) { av[j] = expf(ev[j] - bmax); ls += av[j]; }
  }
  float ss = ls;
  #pragma unroll
  for (int off = 32; off >= 1; off >>= 1) ss += __shfl_xor(ss, off, 64);
  if ((tid & 63) == 0) sm.reds[tid >> 6] = ss;
  __syncthreads();
  float Z = sm.reds[0] + sm.reds[1] + sm.reds[2] + sm.reds[3];

  if (write_out) arow[tid] = make_float4(av[0] / Z, av[1] / Z, av[2] / Z, av[3] / Z);

  #pragma unroll
  for (int j = 0; j < 4; j++) {
    if (mt[j] && av[j] != 0.f) {
      float a = av[j] / Z;
      int c = c0 + j;
      const float* rp = pat_rep + (size_t)(f * Cv + c) * Dv;
      float p = pos_cnt[f * Cv + c], n = neg_cnt[f * Cv + c];
      float r = p / (p + n + 1e-6f);
      for (int jj = 0; jj < Dv; jj++) atomicAdd(&sm.vsum[jj], a * rp[jj]);
      atomicAdd(&sm.vsum[Dv], a * r);
    }
  }
  __syncthreads();
  float vreg = 0.f;
  if (tid < D1) {
    float s = b_v[f * D1 + tid];
    const float* w = W_v + (f * D1 + tid) * D1;
    for (int j = 0; j < D1; j++) s += w[j] * sm.vsum[j];
    vreg = s;
  }
  __syncthreads();
  if (tid < D1) {
    float vd = fm ? vreg : 0.f;
    sm.vsum[tid] = vd;
    if (write_out) srep_out[(b * Fv + f) * D1 + tid] = vd;
  }
}

// ---------------------------------------------------------------------------
// Single fused kernel. Blocks [0,2048): attention per (f,b) -> a_all, srep.
// Blocks [2048,2304): cali per b (recompute codes + per-f match; direct
// write, no atomics, no zero-init).
// ---------------------------------------------------------------------------
__global__ __launch_bounds__(256) void fused(
    const float* __restrict__ tdata, const int* __restrict__ f_mask,
    const float* __restrict__ centers, const int* __restrict__ pat,
    const float* __restrict__ pat_rep, const float* __restrict__ pos_cnt,
    const float* __restrict__ neg_cnt,
    const float* __restrict__ W_q, const float* __restrict__ b_q,
    const float* __restrict__ W_k, const float* __restrict__ b_k,
    const float* __restrict__ W_v, const float* __restrict__ b_v,
    const float* __restrict__ W_pred,
    float* __restrict__ cali, float* __restrict__ a_out,
    float* __restrict__ srep_out) {
  __shared__ SM sm;
  int blk = blockIdx.x, tid = threadIdx.x;

  if (blk < Fv * Bv) {
    // ---------------- attention block (b,f) ----------------
    int f = blk >> 8, b = blk & 255;
    compute_codes(sm, b, tdata, f_mask, centers);
    int mloc = (tid < Tv) ? f_mask[(b * Tv + tid) * Fv + f] : 0;
    bool fmw = __any(mloc != 0);           // valid in wave 0
    if (tid == 0) sm.fm_any = fmw ? 1 : 0;
    attn_feature(sm, b, f, true, &sm.fm_any, tdata, pat, pat_rep,
                 pos_cnt, neg_cnt, W_q, b_q, W_k, b_k, W_v, b_v,
                 a_out, srep_out);
  } else {
    // ---------------- cali block (b) ----------------
    int b = blk - Fv * Bv;
    compute_codes(sm, b, tdata, f_mask, centers);
    if (tid < Fv) sm.fm_arr[tid] = 0;
    __syncthreads();
    if (tid < Tv * Fv) {
      int t = tid >> 3, ffi = tid & 7;
      if (f_mask[(b * Tv + t) * Fv + ffi] != 0) sm.fm_arr[ffi] = 1;
    }
    for (int f = 0; f < Fv; f++) {
      attn_feature(sm, b, f, false, &sm.fm_arr[f], tdata, pat, pat_rep,
                   pos_cnt, neg_cnt, W_q, b_q, W_k, b_k, W_v, b_v,
                   a_out, srep_out);
      __syncthreads();
      if (tid < D1) sm.srep_all[f * D1 + tid] = sm.vsum[tid];
      __syncthreads();
    }
    if (tid < Ov) {
      const float* w = W_pred + tid * (Fv * D1);
      float acc = 0.f;
      #pragma unroll 8
      for (int i = 0; i < Fv * D1; i++) acc += sm.srep_all[i] * w[i];
      cali[b * Ov + tid] = acc;
    }
  }
}

extern "C" void kernel_launch(void* const* d_in, const int* in_sizes, int n_in,
                              void* d_out, int out_size, void* d_ws, size_t ws_size,
                              hipStream_t stream) {
  const float* tdata   = (const float*)d_in[0];
  const int*   f_mask  = (const int*)d_in[1];
  const float* centers = (const float*)d_in[2];
  const int*   pat     = (const int*)d_in[3];
  const float* pat_rep = (const float*)d_in[4];
  const float* pos_cnt = (const float*)d_in[5];
  const float* neg_cnt = (const float*)d_in[6];
  const float* W_q     = (const float*)d_in[7];
  const float* b_q     = (const float*)d_in[8];
  const float* W_k     = (const float*)d_in[9];
  const float* b_k     = (const float*)d_in[10];
  const float* W_v     = (const float*)d_in[11];
  const float* b_v     = (const float*)d_in[12];
  const float* W_pred  = (const float*)d_in[13];

  float* out = (float*)d_out;
  float* cali = out;                                        // Bv*Ov
  float* a_all = out + (Bv * Ov);                           // Fv*Bv*Cv
  float* srep = out + (Bv * Ov) + (Fv * (size_t)Bv * Cv);   // Bv*Fv*D1

  fused<<<Fv * Bv + Bv, 256, 0, stream>>>(
      tdata, f_mask, centers, pat, pat_rep, pos_cnt, neg_cnt,
      W_q, b_q, W_k, b_k, W_v, b_v, W_pred,
      cali, a_all, srep);
}

// Round 5
// 124.644 us; speedup vs baseline: 3.0973x; 3.0973x over previous
//
#include <hip/hip_runtime.h>
#include <math.h>

#define Bv 256
#define Tv 16
#define Fv 8
#define Dv 32
#define Kv 64
#define Cv 1024
#define Ov 2
#define D1 33        // D+1
#define CSTRIDE 33   // padded LDS row stride (dwords): bank=(row+col)%32 spreads

typedef unsigned long long u64;
typedef unsigned char u8;

struct SM {
  float cen[4 * Kv * CSTRIDE];   // one pass: 4 ff x 64 rows x 33   (33,792 B)
  float xsh[Tv * Fv * Dv];       // tdata slab for this b            (16,384 B)
  u64   cds[Tv];                 // packed code bytes per t
  int   fmask[Tv * Fv];
  int   fm_arr[Fv];
  int   anyf[Fv][4];
  float srep_all[Fv * D1];
  float iqs[Dv], zs[D1 + 1], vsum[D1];
  float redm[4], reds[4];
};                               // ~52.5 KB total

// ---------------------------------------------------------------------------
// One codes pass: stage centers for ff in [pass*4, pass*4+4) into padded LDS,
// then wave w handles ff=pass*4+w, lane=k. Center row in registers; x rows
// read as wave-uniform LDS broadcasts (conflict-free). First-index tiebreak
// argmin via 6-step shfl. Writes masked code byte into sm.cds.
// ---------------------------------------------------------------------------
__device__ __forceinline__ void codes_pass(SM& sm, int pass,
    const float* __restrict__ centers) {
  int tid = threadIdx.x;
  int w = tid >> 6, lane = tid & 63;
  // stage 8192 floats (4 ff x 64 rows x 32), coalesced read, padded write:
  // bank=(row*33+col)%32=(row+col)%32 -> spread
  const float4* src = (const float4*)(centers + pass * 4 * Kv * Dv);
  #pragma unroll
  for (int it = 0; it < 8; it++) {
    int g4 = tid + it * 256;
    float4 v = src[g4];
    int g = g4 * 4;
    int row = g >> 5, col = g & 31;
    float* dst = &sm.cen[row * CSTRIDE + col];
    dst[0] = v.x; dst[1] = v.y; dst[2] = v.z; dst[3] = v.w;
  }
  __syncthreads();
  int ff = pass * 4 + w;
  // own center row -> registers (scalar b32 reads, bank=(lane+j)%32 spread)
  float crow[Dv];
  float cc = 0.f;
  const float* rowp = &sm.cen[(w * Kv + lane) * CSTRIDE];
  #pragma unroll
  for (int j = 0; j < Dv; j++) { float cv = rowp[j]; crow[j] = cv; cc += cv * cv; }
  for (int t = 0; t < Tv; t++) {
    const float4* xp = (const float4*)&sm.xsh[(t * Fv + ff) * Dv];  // uniform
    float dot = 0.f;
    #pragma unroll
    for (int i = 0; i < 8; i++) {
      float4 xv = xp[i];
      dot += crow[i*4+0]*xv.x + crow[i*4+1]*xv.y + crow[i*4+2]*xv.z + crow[i*4+3]*xv.w;
    }
    float bd = cc - 2.0f * dot;   // ||x||^2 dropped: argmin-invariant
    int bk = lane;
    #pragma unroll
    for (int off = 32; off >= 1; off >>= 1) {
      float od = __shfl_xor(bd, off, 64);
      int ok = __shfl_xor(bk, off, 64);
      if (od < bd || (od == bd && ok < bk)) { bd = od; bk = ok; }  // first idx
    }
    if (lane == 0) {
      int m = sm.fmask[t * Fv + ff];
      ((u8*)sm.cds)[t * Fv + ff] = (u8)(m != 0 ? bk + 2 : 1);
    }
  }
  __syncthreads();
}

// ---------------------------------------------------------------------------
// Single kernel, 256 blocks (block=b), 256 threads. Codes once per b, then
// all 8 features' match/softmax/outputs + inline cali. No workspace.
// ---------------------------------------------------------------------------
__global__ __launch_bounds__(256) void fused(
    const float* __restrict__ tdata, const int* __restrict__ f_mask,
    const float* __restrict__ centers, const int* __restrict__ pat,
    const float* __restrict__ pat_rep, const float* __restrict__ pos_cnt,
    const float* __restrict__ neg_cnt,
    const float* __restrict__ W_q, const float* __restrict__ b_q,
    const float* __restrict__ W_k, const float* __restrict__ b_k,
    const float* __restrict__ W_v, const float* __restrict__ b_v,
    const float* __restrict__ W_pred,
    float* __restrict__ cali, float* __restrict__ a_out,
    float* __restrict__ srep_out) {
  __shared__ SM sm;
  int b = blockIdx.x, tid = threadIdx.x;

  // ---- stage x slab (coalesced) + fmask ----
  {
    const float4* src = (const float4*)(tdata + (size_t)b * (Tv * Fv * Dv));
    float4* dst = (float4*)sm.xsh;
    #pragma unroll
    for (int it = 0; it < 4; it++) dst[tid + it * 256] = src[tid + it * 256];
    if (tid < Tv * Fv) sm.fmask[tid] = f_mask[b * (Tv * Fv) + tid];
  }
  codes_pass(sm, 0, centers);    // first sync inside covers staging above
  if (tid < Fv) {
    int a = 0;
    #pragma unroll
    for (int t = 0; t < Tv; t++) a |= sm.fmask[t * Fv + tid];
    sm.fm_arr[tid] = (a != 0);
  }
  codes_pass(sm, 1, centers);    // ends with __syncthreads -> cds/fm_arr valid

  u64 creg[Tv];
  #pragma unroll
  for (int t = 0; t < Tv; t++) creg[t] = sm.cds[t];

  for (int f = 0; f < Fv; f++) {
    // ---- pattern pack + match; c = tid + 256*jj (coalesced pat reads) ----
    u64 pp[4], cm[4];
    bool mt[4];
    #pragma unroll
    for (int jj = 0; jj < 4; jj++) {
      int c = tid + (jj << 8);
      const int4* pr = (const int4*)(pat + ((size_t)f * Cv + c) * Fv);
      int4 pa = pr[0], pb = pr[1];
      int vals[8] = {pa.x, pa.y, pa.z, pa.w, pb.x, pb.y, pb.z, pb.w};
      u64 P = 0, M = 0;
      #pragma unroll
      for (int k = 0; k < 8; k++) {
        P |= ((u64)(vals[k] & 0xFF)) << (8 * k);
        if (vals[k] != 0) M |= 0xFFull << (8 * k);
      }
      pp[jj] = P; cm[jj] = M;
      bool m = false;
      #pragma unroll
      for (int t = 0; t < Tv; t++) m = m || (((creg[t] ^ P) & M) == 0ull);
      mt[jj] = m;
    }
    bool lany = mt[0] || mt[1] || mt[2] || mt[3];
    bool wv = __any((int)lany);
    if ((tid & 63) == 0) sm.anyf[f][tid >> 6] = wv ? 1 : 0;
    __syncthreads();
    bool anym = (sm.anyf[f][0] | sm.anyf[f][1] | sm.anyf[f][2] | sm.anyf[f][3]) != 0;
    bool fm = sm.fm_arr[f] != 0;
    float* arow = a_out + (size_t)(f * Bv + b) * Cv;

    if (!anym) {
      // ---------- common (degenerate) path ----------
      const float uu = 1.0f / 1024.0f;
      #pragma unroll
      for (int jj = 0; jj < 4; jj++) arow[tid + (jj << 8)] = uu;
      if (tid < D1) {
        float vd = fm ? b_v[f * D1 + tid] : 0.f;
        sm.srep_all[f * D1 + tid] = vd;
        srep_out[(b * Fv + f) * D1 + tid] = vd;
      }
      continue;
    }

    // ---------- rare full path (block-uniform branch) ----------
    if (tid < D1) sm.vsum[tid] = 0.f;
    __syncthreads();
    if (tid < Dv) {
      const float* xq = &sm.xsh[((Tv - 1) * Fv + f) * Dv];   // query row
      const float* wq = W_q + (f * Dv + tid) * Dv;
      float s = b_q[f * Dv + tid];
      #pragma unroll
      for (int j = 0; j < Dv; j++) s += wq[j] * xq[j];
      sm.iqs[tid] = s;
    }
    __syncthreads();
    if (tid < D1) {
      float s = 0.f;
      #pragma unroll
      for (int i = 0; i < Dv; i++) s += W_k[(f * Dv + i) * D1 + tid] * sm.iqs[i];
      sm.zs[tid] = s;
    }
    if (tid == D1) {
      float s = 0.f;
      #pragma unroll
      for (int i = 0; i < Dv; i++) s += b_k[f * Dv + i] * sm.iqs[i];
      sm.zs[D1] = s;
    }
    __syncthreads();

    float ev[4];
    float lmax = -INFINITY;
    #pragma unroll
    for (int jj = 0; jj < 4; jj++) {
      ev[jj] = 0.f;
      if (mt[jj]) {
        int c = tid + (jj << 8);
        const float* rp = pat_rep + (size_t)(f * Cv + c) * Dv;
        float p = pos_cnt[f * Cv + c], n = neg_cnt[f * Cv + c];
        float r = p / (p + n + 1e-6f);
        float s = sm.zs[D1] + r * sm.zs[Dv];
        for (int j = 0; j < Dv; j++) s += rp[j] * sm.zs[j];
        ev[jj] = s;
        lmax = fmaxf(lmax, s);
      }
    }
    float mx = lmax;
    #pragma unroll
    for (int off = 32; off >= 1; off >>= 1) mx = fmaxf(mx, __shfl_xor(mx, off, 64));
    if ((tid & 63) == 0) sm.redm[tid >> 6] = mx;
    __syncthreads();
    float bmax = fmaxf(fmaxf(sm.redm[0], sm.redm[1]), fmaxf(sm.redm[2], sm.redm[3]));

    float av[4] = {0.f, 0.f, 0.f, 0.f};
    float ls = 0.f;
    #pragma unroll
    for (int jj = 0; jj < 4; jj++) {
      if (mt[jj]) { av[jj] = expf(ev[jj] - bmax); ls += av[jj]; }
    }
    float ss = ls;
    #pragma unroll
    for (int off = 32; off >= 1; off >>= 1) ss += __shfl_xor(ss, off, 64);
    if ((tid & 63) == 0) sm.reds[tid >> 6] = ss;
    __syncthreads();
    float Z = sm.reds[0] + sm.reds[1] + sm.reds[2] + sm.reds[3];

    #pragma unroll
    for (int jj = 0; jj < 4; jj++) {
      float a = av[jj] / Z;
      arow[tid + (jj << 8)] = a;          // exact 0 for unmatched
      if (mt[jj] && av[jj] != 0.f) {
        int c = tid + (jj << 8);
        const float* rp = pat_rep + (size_t)(f * Cv + c) * Dv;
        float p = pos_cnt[f * Cv + c], n = neg_cnt[f * Cv + c];
        float r = p / (p + n + 1e-6f);
        for (int j = 0; j < Dv; j++) atomicAdd(&sm.vsum[j], a * rp[j]);
        atomicAdd(&sm.vsum[Dv], a * r);
      }
    }
    __syncthreads();
    float vreg = 0.f;
    if (tid < D1) {
      float s = b_v[f * D1 + tid];
      const float* wvp = W_v + (f * D1 + tid) * D1;
      for (int j = 0; j < D1; j++) s += wvp[j] * sm.vsum[j];
      vreg = s;
    }
    __syncthreads();
    if (tid < D1) {
      float vd = fm ? vreg : 0.f;
      sm.srep_all[f * D1 + tid] = vd;
      srep_out[(b * Fv + f) * D1 + tid] = vd;
    }
  }

  __syncthreads();
  // ---- cali: wave 0, 32 lanes per output o ----
  if (tid < 64) {
    int o = tid >> 5, l = tid & 31;
    const float* wp = W_pred + o * (Fv * D1);
    float acc = 0.f;
    for (int i = l; i < Fv * D1; i += 32) acc += sm.srep_all[i] * wp[i];
    #pragma unroll
    for (int off = 16; off >= 1; off >>= 1) acc += __shfl_xor(acc, off, 64);
    if (l == 0) cali[b * Ov + o] = acc;
  }
}

extern "C" void kernel_launch(void* const* d_in, const int* in_sizes, int n_in,
                              void* d_out, int out_size, void* d_ws, size_t ws_size,
                              hipStream_t stream) {
  const float* tdata   = (const float*)d_in[0];
  const int*   f_mask  = (const int*)d_in[1];
  const float* centers = (const float*)d_in[2];
  const int*   pat     = (const int*)d_in[3];
  const float* pat_rep = (const float*)d_in[4];
  const float* pos_cnt = (const float*)d_in[5];
  const float* neg_cnt = (const float*)d_in[6];
  const float* W_q     = (const float*)d_in[7];
  const float* b_q     = (const float*)d_in[8];
  const float* W_k     = (const float*)d_in[9];
  const float* b_k     = (const float*)d_in[10];
  const float* W_v     = (const float*)d_in[11];
  const float* b_v     = (const float*)d_in[12];
  const float* W_pred  = (const float*)d_in[13];

  float* out = (float*)d_out;
  float* cali = out;                                        // Bv*Ov
  float* a_all = out + (Bv * Ov);                           // Fv*Bv*Cv
  float* srep = out + (Bv * Ov) + (Fv * (size_t)Bv * Cv);   // Bv*Fv*D1

  fused<<<Bv, 256, 0, stream>>>(
      tdata, f_mask, centers, pat, pat_rep, pos_cnt, neg_cnt,
      W_q, b_q, W_k, b_k, W_v, b_v, W_pred,
      cali, a_all, srep);
}

// Round 6
// 101.661 us; speedup vs baseline: 3.7976x; 1.2261x over previous
//
#include <hip/hip_runtime.h>
#include <math.h>

#define Bv 256
#define Tv 16
#define Fv 8
#define Dv 32
#define Kv 64
#define Cv 1024
#define Ov 2
#define D1 33   // D+1

typedef unsigned long long u64;
typedef unsigned char u8;

struct SM {
  float xsh[Tv * Fv * Dv];   // [t][ff][j] identity layout, uniform reads only (16 KB)
  u64   cds[Tv];             // packed code bytes per t (u8-aliased writes)
  int   fmask[Tv * Fv];
  float srep_all[Fv * D1];
  float vsum[Fv][D1];        // per-wave rare-path PV scratch
};                           // ~19 KB

// ---------------------------------------------------------------------------
// Single kernel: grid = 256 (block = b), 512 threads = 8 waves.
// Wave w owns feature f = w for everything; only 3 block barriers.
// ---------------------------------------------------------------------------
__global__ __launch_bounds__(512) void fused(
    const float* __restrict__ tdata, const int* __restrict__ f_mask,
    const float* __restrict__ centers, const int* __restrict__ pat,
    const float* __restrict__ pat_rep, const float* __restrict__ pos_cnt,
    const float* __restrict__ neg_cnt,
    const float* __restrict__ W_q, const float* __restrict__ b_q,
    const float* __restrict__ W_k, const float* __restrict__ b_k,
    const float* __restrict__ W_v, const float* __restrict__ b_v,
    const float* __restrict__ W_pred,
    float* __restrict__ cali, float* __restrict__ a_out,
    float* __restrict__ srep_out) {
  __shared__ SM sm;
  int b = blockIdx.x, tid = threadIdx.x;
  int w = tid >> 6, lane = tid & 63;   // wave index = feature index

  // ---- stage x slab + f_mask (coalesced, identity layout) ----
  {
    const float4* src = (const float4*)(tdata + (size_t)b * (Tv * Fv * Dv));
    float4* dst = (float4*)sm.xsh;
    dst[tid] = src[tid];
    dst[tid + 512] = src[tid + 512];
    if (tid < Tv * Fv) sm.fmask[tid] = f_mask[b * (Tv * Fv) + tid];
  }
  __syncthreads();   // barrier 1

  // ---- codes: wave w = feature w, lane = center k ----
  {
    const float4* cp = (const float4*)(centers + (size_t)(w * Kv + lane) * Dv);
    float4 c4[8];
    float cc = 0.f;
    #pragma unroll
    for (int i = 0; i < 8; i++) {
      float4 v = cp[i];
      c4[i] = v;
      cc += v.x * v.x + v.y * v.y + v.z * v.z + v.w * v.w;
    }
    #pragma unroll
    for (int t = 0; t < Tv; t += 2) {
      const float4* x0 = (const float4*)&sm.xsh[(t * Fv + w) * Dv];        // uniform
      const float4* x1 = (const float4*)&sm.xsh[((t + 1) * Fv + w) * Dv];  // uniform
      float dot0 = 0.f, dot1 = 0.f;
      #pragma unroll
      for (int i = 0; i < 8; i++) {
        float4 a = x0[i], bq = x1[i];
        dot0 += c4[i].x * a.x + c4[i].y * a.y + c4[i].z * a.z + c4[i].w * a.w;
        dot1 += c4[i].x * bq.x + c4[i].y * bq.y + c4[i].z * bq.z + c4[i].w * bq.w;
      }
      float d0 = cc - 2.0f * dot0;   // ||x||^2 dropped: argmin-invariant (validated R3/R5)
      float d1 = cc - 2.0f * dot1;
      float m0 = d0, m1 = d1;
      #pragma unroll
      for (int off = 1; off <= 32; off <<= 1) {   // two independent chains (ILP)
        m0 = fminf(m0, __shfl_xor(m0, off, 64));
        m1 = fminf(m1, __shfl_xor(m1, off, 64));
      }
      u64 bl0 = __ballot(d0 == m0);
      u64 bl1 = __ballot(d1 == m1);
      int k0 = __ffsll(bl0) - 1;     // lowest lane with min = first-index tiebreak
      int k1 = __ffsll(bl1) - 1;
      if (lane == 0) {
        ((u8*)sm.cds)[t * Fv + w] = sm.fmask[t * Fv + w] ? (u8)(k0 + 2) : (u8)1;
        ((u8*)sm.cds)[(t + 1) * Fv + w] = sm.fmask[(t + 1) * Fv + w] ? (u8)(k1 + 2) : (u8)1;
      }
    }
  }
  __syncthreads();   // barrier 2

  int f = w;
  u64 creg[Tv];
  #pragma unroll
  for (int t = 0; t < Tv; t++) creg[t] = sm.cds[t];   // uniform reads

  int fmlv = (lane < Tv) ? sm.fmask[lane * Fv + f] : 0;
  bool fm = __any(fmlv != 0);

  // ---- match: 16 c per lane, c = jj*64 + lane (coalesced pat reads) ----
  unsigned mask16 = 0u;
  #pragma unroll 4
  for (int jj = 0; jj < 16; jj++) {
    int c = (jj << 6) + lane;
    const int4* pr = (const int4*)(pat + ((size_t)f * Cv + c) * Fv);
    int4 pa = pr[0], pb = pr[1];
    int vals[8] = {pa.x, pa.y, pa.z, pa.w, pb.x, pb.y, pb.z, pb.w};
    u64 P = 0, M = 0;
    #pragma unroll
    for (int k = 0; k < 8; k++) {
      P |= ((u64)(vals[k] & 0xFF)) << (8 * k);
      if (vals[k] != 0) M |= 0xFFull << (8 * k);
    }
    u64 pm = P & M;
    bool m = false;
    #pragma unroll
    for (int t = 0; t < Tv; t++) m = m || ((creg[t] & M) == pm);
    if (m) mask16 |= (1u << jj);
  }
  bool anym = __any(mask16 != 0u);

  float* arow = a_out + (size_t)(f * Bv + b) * Cv;

  if (!anym) {
    // ---------------- common (degenerate) path: wave-local ----------------
    const float uu = 1.0f / 1024.0f;
    #pragma unroll
    for (int jj = 0; jj < 16; jj++) arow[(jj << 6) + lane] = uu;
    if (lane < D1) {
      float vd = fm ? b_v[f * D1 + lane] : 0.f;
      srep_out[(b * Fv + f) * D1 + lane] = vd;
      sm.srep_all[f * D1 + lane] = vd;
    }
  } else {
    // ---------------- rare full path: wave-local, NO barriers ----------------
    if (lane < D1) sm.vsum[f][lane] = 0.f;
    float iqv = 0.f;
    if (lane < Dv) {
      const float* wq = W_q + (f * Dv + lane) * Dv;
      const float* xq = &sm.xsh[((Tv - 1) * Fv + f) * Dv];
      float s = b_q[f * Dv + lane];
      for (int j = 0; j < Dv; j++) s += wq[j] * xq[j];
      iqv = s;
    }
    // z_j (lane<33) and bk·iq (lane 33) via shfl broadcast of iq
    float zv = 0.f;
    for (int i = 0; i < Dv; i++) {
      float iqi = __shfl(iqv, i, 64);
      float coef = 0.f;
      if (lane < D1) coef = W_k[(f * Dv + i) * D1 + lane];
      else if (lane == D1) coef = b_k[f * Dv + i];
      zv += coef * iqi;
    }
    float ev[16];
    float lmax = -INFINITY;
    for (int jj = 0; jj < 16; jj++) {
      ev[jj] = 0.f;
      if (mask16 & (1u << jj)) {
        int c = (jj << 6) + lane;
        const float* rp = pat_rep + ((size_t)f * Cv + c) * Dv;
        float p = pos_cnt[f * Cv + c], n = neg_cnt[f * Cv + c];
        float r = p / (p + n + 1e-6f);
        float s = __shfl(zv, D1, 64) + r * __shfl(zv, Dv, 64);
        for (int j = 0; j < Dv; j++) s += rp[j] * __shfl(zv, j, 64);
        ev[jj] = s;
        lmax = fmaxf(lmax, s);
      }
    }
    float bm = lmax;
    #pragma unroll
    for (int off = 1; off <= 32; off <<= 1) bm = fmaxf(bm, __shfl_xor(bm, off, 64));
    float ls = 0.f;
    for (int jj = 0; jj < 16; jj++) {
      if (mask16 & (1u << jj)) { ev[jj] = expf(ev[jj] - bm); ls += ev[jj]; }
    }
    float Zs = ls;
    #pragma unroll
    for (int off = 1; off <= 32; off <<= 1) Zs += __shfl_xor(Zs, off, 64);
    for (int jj = 0; jj < 16; jj++) {
      int c = (jj << 6) + lane;
      bool hit = (mask16 & (1u << jj)) != 0u;
      float a = hit ? ev[jj] / Zs : 0.f;   // unmatched: exact 0 (ref: exp underflow)
      arow[c] = a;
      if (hit && a != 0.f) {
        const float* rp = pat_rep + ((size_t)f * Cv + c) * Dv;
        float p = pos_cnt[f * Cv + c], n = neg_cnt[f * Cv + c];
        float r = p / (p + n + 1e-6f);
        for (int j = 0; j < Dv; j++) atomicAdd(&sm.vsum[f][j], a * rp[j]);
        atomicAdd(&sm.vsum[f][Dv], a * r);
      }
    }
    if (lane < D1) {   // v = Wv·(sum a·rep) + bv   (wave-local LDS, waitcnt by compiler)
      float s = b_v[f * D1 + lane];
      const float* wvp = W_v + (f * D1 + lane) * D1;
      for (int j = 0; j < D1; j++) s += wvp[j] * sm.vsum[f][j];
      float vd = fm ? s : 0.f;
      srep_out[(b * Fv + f) * D1 + lane] = vd;
      sm.srep_all[f * D1 + lane] = vd;
    }
  }

  __syncthreads();   // barrier 3
  // ---- cali: wave 0, 32 lanes per output o ----
  if (tid < 64) {
    int o = tid >> 5, l = tid & 31;
    const float* wp = W_pred + o * (Fv * D1);
    float acc = 0.f;
    for (int i = l; i < Fv * D1; i += 32) acc += sm.srep_all[i] * wp[i];
    #pragma unroll
    for (int off = 16; off >= 1; off >>= 1) acc += __shfl_xor(acc, off, 64);
    if (l == 0) cali[b * Ov + o] = acc;
  }
}

extern "C" void kernel_launch(void* const* d_in, const int* in_sizes, int n_in,
                              void* d_out, int out_size, void* d_ws, size_t ws_size,
                              hipStream_t stream) {
  const float* tdata   = (const float*)d_in[0];
  const int*   f_mask  = (const int*)d_in[1];
  const float* centers = (const float*)d_in[2];
  const int*   pat     = (const int*)d_in[3];
  const float* pat_rep = (const float*)d_in[4];
  const float* pos_cnt = (const float*)d_in[5];
  const float* neg_cnt = (const float*)d_in[6];
  const float* W_q     = (const float*)d_in[7];
  const float* b_q     = (const float*)d_in[8];
  const float* W_k     = (const float*)d_in[9];
  const float* b_k     = (const float*)d_in[10];
  const float* W_v     = (const float*)d_in[11];
  const float* b_v     = (const float*)d_in[12];
  const float* W_pred  = (const float*)d_in[13];

  float* out = (float*)d_out;
  float* cali = out;                                        // Bv*Ov
  float* a_all = out + (Bv * Ov);                           // Fv*Bv*Cv
  float* srep = out + (Bv * Ov) + (Fv * (size_t)Bv * Cv);   // Bv*Fv*D1

  fused<<<Bv, 512, 0, stream>>>(
      tdata, f_mask, centers, pat, pat_rep, pos_cnt, neg_cnt,
      W_q, b_q, W_k, b_k, W_v, b_v, W_pred,
      cali, a_all, srep);
}